// Round 26
// baseline (111.903 us; speedup 1.0000x reference)
//
#include <hip/hip_runtime.h>
#include <hip/hip_fp16.h>

#define FIN 64
#define CAP 48        // per-row CSR slots; max deg ~45 (Poisson 16, N=50K)
#define BINSH 8       // bin = row >> 8 (256 rows/bin)
#define NBINMAX 256
#define PCAP 5120     // per-bin edge capacity: mean ~4082, +16 sigma
#define TILE_B 8192   // edges per sort tile (32 per thread, lp-only registers)

typedef __attribute__((ext_vector_type(8))) short short8v;   // 8 bf16
typedef __attribute__((ext_vector_type(4))) float f32x4v;    // 4 f32 acc

__device__ __forceinline__ unsigned pk_bf16(float a, float b) {  // 2xf32 -> packed bf16 (RNE)
    unsigned ua = __builtin_bit_cast(unsigned, a);
    unsigned ub = __builtin_bit_cast(unsigned, b);
    ua = (ua + 0x7FFFu + ((ua >> 16) & 1u)) >> 16;
    ub = (ub + 0x7FFFu + ((ub >> 16) & 1u)) >> 16;
    return ua | (ub << 16);
}

// ---------------------------------------------------------------------------
// P1 fused: (A) support GEMM via bf16 MFMA 16x16x32 (R25 config);
//           (B) tile counting-sort, 8192 edges/tile — lp[32] only across the
//               scan; write phase reloads eidx (L2-hot) and recomputes bn/pay.
__global__ __launch_bounds__(256) void p1_kernel(const float* __restrict__ x,
                                                 const float* __restrict__ weight,
                                                 __half* __restrict__ sup,
                                                 const int* __restrict__ eidx,
                                                 int* __restrict__ gcur,
                                                 int* __restrict__ part,
                                                 int n, int e_total, int sblocks) {
    const int t = threadIdx.x;
    __shared__ unsigned short xb[32][72];          // 4.6 KB bf16 x-tile
    __shared__ int hist[NBINMAX], lbase[NBINMAX], gbase[NBINMAX];
    __shared__ int wsum[4];

    // ---- phase A: MFMA support ----
    const int rowbase = blockIdx.x * 32;
    if (rowbase < n) {
        {   // stage x tile as bf16
            int nrows = n - rowbase; if (nrows > 32) nrows = 32;
            int nf2 = nrows * 32;                  // float2 count
            const float2* __restrict__ x2 = (const float2*)(x + (size_t)rowbase * 64);
            #pragma unroll
            for (int j = 0; j < 4; ++j) {
                int idx = t + j * 256;
                if (idx < nf2) {
                    float2 v = x2[idx];
                    int r = idx >> 5, c2 = idx & 31;
                    *(unsigned*)&xb[r][c2 * 2] = pk_bf16(v.x, v.y);
                }
            }
        }
        __syncthreads();

        const int lane = t & 63;
        const int w4 = t >> 6;
        const int lm = lane & 15, lg = lane >> 4;

        short8v a[2][2];
        #pragma unroll
        for (int mt = 0; mt < 2; ++mt)
            #pragma unroll
            for (int kb = 0; kb < 2; ++kb)
                a[mt][kb] = *(const short8v*)&xb[mt * 16 + lm][kb * 32 + lg * 8];

        f32x4v acc[2][4];
        #pragma unroll
        for (int mt = 0; mt < 2; ++mt)
            #pragma unroll
            for (int nt = 0; nt < 4; ++nt)
                acc[mt][nt] = (f32x4v){0.f, 0.f, 0.f, 0.f};

        #pragma unroll
        for (int nt = 0; nt < 4; ++nt) {
            const int col = (w4 * 4 + nt) * 16 + lm;
            short8v bfr[2];
            #pragma unroll
            for (int kb = 0; kb < 2; ++kb) {
                short8v bb;
                #pragma unroll
                for (int j = 0; j < 8; ++j) {
                    float wv = weight[(kb * 32 + lg * 8 + j) * 256 + col];
                    unsigned u = __builtin_bit_cast(unsigned, wv);
                    bb[j] = (short)((u + 0x7FFFu + ((u >> 16) & 1u)) >> 16);
                }
                bfr[kb] = bb;
            }
            #pragma unroll
            for (int mt = 0; mt < 2; ++mt) {
                acc[mt][nt] = __builtin_amdgcn_mfma_f32_16x16x32_bf16(a[mt][0], bfr[0], acc[mt][nt], 0, 0, 0);
                acc[mt][nt] = __builtin_amdgcn_mfma_f32_16x16x32_bf16(a[mt][1], bfr[1], acc[mt][nt], 0, 0, 0);
            }
        }

        #pragma unroll
        for (int mt = 0; mt < 2; ++mt) {
            const int row0 = rowbase + mt * 16 + lg * 4;
            #pragma unroll
            for (int reg = 0; reg < 4; ++reg) {
                if (row0 + reg < n) {
                    #pragma unroll
                    for (int nt = 0; nt < 4; ++nt) {
                        int col = (w4 * 4 + nt) * 16 + lm;
                        sup[(size_t)(row0 + reg) * 256 + col] = __float2half(acc[mt][nt][reg]);
                    }
                }
            }
        }
    }

    // ---- phase B: counting-sort an 8192-edge tile (blocks < sblocks) ----
    if (blockIdx.x < sblocks) {
        int nz = 0;
        #pragma unroll
        for (int j = 1; j < 16; j += 2) nz |= eidx[j];   // broadcast scalar loads
        const int is64 = (nz == 0);

        hist[t] = 0;
        __syncthreads();

        const int base = blockIdx.x * TILE_B;
        int nv = e_total - base;
        if (nv > TILE_B) nv = TILE_B;
        if (nv < 0) nv = 0;

        int lp[32];
        // load phase: 16 pairs/thread, hist atomics; keep only lp.
        #pragma unroll
        for (int i = 0; i < 16; ++i) {
            const int pl = t + 256 * i;              // local pair id
            const int pg = (base >> 1) + pl;         // global pair id
            int r0 = 0, r1 = 0, v0 = 0, v1 = 0;
            if (2 * pl < nv) {
                if (is64) {
                    int4 rr = ((const int4*)eidx)[pg];
                    r0 = rr.x; v0 = 1;
                    if (2 * pl + 1 < nv) { r1 = rr.z; v1 = 1; }
                } else {
                    int2 rr = ((const int2*)eidx)[pg];
                    r0 = rr.x; v0 = 1;
                    if (2 * pl + 1 < nv) { r1 = rr.y; v1 = 1; }
                }
            }
            lp[2 * i]     = v0 ? atomicAdd(&hist[r0 >> BINSH], 1) : 0;
            lp[2 * i + 1] = v1 ? atomicAdd(&hist[r1 >> BINSH], 1) : 0;
        }
        __syncthreads();

        {   // block exclusive scan over 256 hist entries
            const int lane = t & 63;
            const int w = t >> 6;
            int h = hist[t];
            int s = h;
            #pragma unroll
            for (int off = 1; off < 64; off <<= 1) {
                int u = __shfl_up(s, off, 64);
                if (lane >= off) s += u;
            }
            if (lane == 63) wsum[w] = s;
            __syncthreads();
            if (t == 0) {
                int a0 = 0;
                #pragma unroll
                for (int q = 0; q < 4; ++q) { int u = wsum[q]; wsum[q] = a0; a0 += u; }
            }
            __syncthreads();
            lbase[t] = s - h + wsum[w];
            gbase[t] = (h > 0) ? atomicAdd(&gcur[t], h) : 0;
        }
        __syncthreads();

        // write phase: reload eidx (L2-hot), recompute bn/pay, use saved lp.
        #pragma unroll
        for (int i = 0; i < 16; ++i) {
            const int pl = t + 256 * i;
            const int pg = (base >> 1) + pl;
            int r0 = 0, c0 = 0, r1 = 0, c1 = 0, v0 = 0, v1 = 0;
            if (2 * pl < nv) {
                if (is64) {
                    int4 rr = ((const int4*)eidx)[pg];
                    int4 cc = ((const int4*)(eidx + 2 * (size_t)e_total))[pg];
                    r0 = rr.x; c0 = cc.x; v0 = 1;
                    if (2 * pl + 1 < nv) { r1 = rr.z; c1 = cc.z; v1 = 1; }
                } else {
                    int2 rr = ((const int2*)eidx)[pg];
                    int2 cc = ((const int2*)(eidx + (size_t)e_total))[pg];
                    r0 = rr.x; c0 = cc.x; v0 = 1;
                    if (2 * pl + 1 < nv) { r1 = rr.y; c1 = cc.y; v1 = 1; }
                }
            }
            if (v0) {
                int b = r0 >> BINSH;
                int dst = gbase[b] + lp[2 * i];
                if (dst < PCAP) part[b * PCAP + dst] = (c0 << 8) | (r0 & 255);
            }
            if (v1) {
                int b = r1 >> BINSH;
                int dst = gbase[b] + lp[2 * i + 1];
                if (dst < PCAP) part[b * PCAP + dst] = (c1 << 8) | (r1 & 255);
            }
        }
    }
}

// ---------------------------------------------------------------------------
// P2: one block per 256-row bin; re-bucket into row-CSR AND precompute the
// Gaussian values. Stores col (4B) + packed 4xfp16 values (8B) per edge.
__global__ __launch_bounds__(1024) void p2_kernel(const int* __restrict__ gcur,
                                                  const int* __restrict__ part,
                                                  const float* __restrict__ spec,
                                                  const float* __restrict__ mu,   // [3][4]
                                                  const float* __restrict__ sig,  // [4]
                                                  int* __restrict__ cnt,
                                                  int* __restrict__ scol,
                                                  uint2* __restrict__ sval, int n) {
    __shared__ int cl[256];
    const int t = threadIdx.x;
    const int b = blockIdx.x;
    const int row0 = b << BINSH;
    if (t < 256) cl[t] = 0;
    __syncthreads();

    float m0[4], m1[4], m2[4], sg[4];
    #pragma unroll
    for (int k = 0; k < 4; ++k) {
        m0[k] = mu[k]; m1[k] = mu[4 + k]; m2[k] = mu[8 + k]; sg[k] = sig[k];
    }

    int nloc = gcur[b];
    if (nloc > PCAP) nloc = PCAP;
    const int* __restrict__ mypart = part + b * PCAP;

    for (int i = t; i < nloc; i += 1024) {
        int e = mypart[i];
        int rl = e & 255;
        int col = ((unsigned)e) >> 8;
        int row = row0 + rl;

        float d0 = spec[row * 3 + 0] - spec[col * 3 + 0];
        float d1 = spec[row * 3 + 1] - spec[col * 3 + 1];
        float d2 = spec[row * 3 + 2] - spec[col * 3 + 2];
        float v[4];
        #pragma unroll
        for (int k = 0; k < 4; ++k) {
            float a = d0 - m0[k], bb = d1 - m1[k], c = d2 - m2[k];
            v[k] = __expf(sg[k] * (-0.5f * (a * a + bb * bb + c * c)));
        }
        union { __half2 h; unsigned u; } p01, p23;
        p01.h = __floats2half2_rn(v[0], v[1]);
        p23.h = __floats2half2_rn(v[2], v[3]);

        int pos = atomicAdd(&cl[rl], 1);
        if (pos < CAP) {
            scol[(size_t)row * CAP + pos] = col;
            sval[(size_t)row * CAP + pos] = make_uint2(p01.u, p23.u);
        }
    }
    __syncthreads();

    int row = row0 + t;
    if (t < 256 && row < n) cnt[row] = (cl[t] > CAP) ? CAP : cl[t];
}

// ---------------------------------------------------------------------------
__device__ __forceinline__ float dot_supv(uint2 p, uint2 pv) {
    float2 f0 = __half22float2(__builtin_bit_cast(__half2, p.x));
    float2 f1 = __half22float2(__builtin_bit_cast(__half2, p.y));
    float2 a0 = __half22float2(__builtin_bit_cast(__half2, pv.x));
    float2 a1 = __half22float2(__builtin_bit_cast(__half2, pv.y));
    return f0.x * a0.x + f0.y * a0.y + f1.x * a1.x + f1.y * a1.y;
}

// One wave per row (grid-stride). 16-deep gather chunks; pad slots masked.
__global__ __launch_bounds__(256, 6) void row_kernel(const int* __restrict__ cnt,
                                                     const int* __restrict__ scol,
                                                     const uint2* __restrict__ sval,
                                                     const __half* __restrict__ sup,
                                                     const float* __restrict__ bias,
                                                     float* __restrict__ out, int n) {
    const int lane = threadIdx.x & 63;
    const int wl = threadIdx.x >> 6;
    const int wv = __builtin_amdgcn_readfirstlane(blockIdx.x * 4 + wl);
    const int NW = gridDim.x * 4;
    const float bias_l = bias[lane];
    const unsigned un = (unsigned)n;

    for (int r = wv; r < n; r += NW) {
        int ec = cnt[r];                          // uniform -> s_load
        if (ec > CAP) ec = CAP;
        const size_t base = (size_t)r * CAP;
        float acc = bias_l;

        for (int j = 0; j < ec; j += 16) {
            int c[16]; uint2 w[16];
            #pragma unroll
            for (int i = 0; i < 16; ++i) {
                int idx = j + i;                  // idx <= 47 < CAP always
                int cc = scol[base + idx];        // uniform -> s_load
                uint2 ww = sval[base + idx];
                bool valid = idx < ec;
                c[i] = ((unsigned)cc < un) ? cc : 0;
                w[i] = valid ? ww : make_uint2(0u, 0u);
            }
            uint2 p[16];
            #pragma unroll
            for (int i = 0; i < 16; ++i)
                p[i] = *(const uint2*)(sup + ((size_t)c[i] * 256 + lane * 4));
            #pragma unroll
            for (int i = 0; i < 16; ++i)
                acc += dot_supv(p[i], w[i]);
        }
        out[(size_t)r * 64 + lane] = acc;
    }
}

// ---------------------------------------------------------------------------
extern "C" void kernel_launch(void* const* d_in, const int* in_sizes, int n_in,
                              void* d_out, int out_size, void* d_ws, size_t ws_size,
                              hipStream_t stream) {
    const float* x      = (const float*)d_in[0];
    const int*   eidx   = (const int*)d_in[1];
    const float* spec   = (const float*)d_in[2];
    const float* weight = (const float*)d_in[3];
    const float* bias   = (const float*)d_in[4];
    const float* mu     = (const float*)d_in[5];
    const float* sig    = (const float*)d_in[6];
    float* out = (float*)d_out;

    const int N = in_sizes[0] / FIN;               // 50000
    const int E = in_sizes[1] / 2;                 // 800000
    const int NB32 = (N + 31) / 32;                // 1563 (covers 98 sort tiles)
    const int SBLK = (E + TILE_B - 1) / TILE_B;    // 98 sort tiles
    const int NBIN = (N + (1 << BINSH) - 1) >> BINSH;  // 196 bins

    char* w = (char*)d_ws;
    size_t off = 0;
    int* gcur = (int*)(w + off);            off += NBINMAX * 4;
    __half* sup = (__half*)(w + off);       off += (size_t)N * 256 * sizeof(__half);  // 25.6 MB
    off = (off + 255) & ~(size_t)255;
    int* cnt = (int*)(w + off);             off += (size_t)N * 4;
    off = (off + 255) & ~(size_t)255;
    int* scol = (int*)(w + off);            off += (size_t)N * CAP * 4;       // 9.6 MB
    off = (off + 255) & ~(size_t)255;
    uint2* sval = (uint2*)(w + off);        off += (size_t)N * CAP * 8;       // 19.2 MB
    off = (off + 255) & ~(size_t)255;
    int* part = (int*)(w + off);            off += (size_t)NBIN * PCAP * 4;   // 4 MB

    hipMemsetAsync(gcur, 0, NBINMAX * 4, stream);
    p1_kernel<<<NB32, 256, 0, stream>>>(x, weight, sup, eidx, gcur, part, N, E, SBLK);
    p2_kernel<<<NBIN, 1024, 0, stream>>>(gcur, part, spec, mu, sig, cnt, scol, sval, N);
    row_kernel<<<1536, 256, 0, stream>>>(cnt, scol, sval, sup, bias, out, N);
}

// Round 27
// 104.915 us; speedup vs baseline: 1.0666x; 1.0666x over previous
//
#include <hip/hip_runtime.h>
#include <hip/hip_fp16.h>

#define FIN 64
#define CAP 48        // per-row CSR slots; max deg ~45 (Poisson 16, N=50K)
#define BINSH 8       // bin = row >> 8 (256 rows/bin)
#define NBINMAX 256
#define PCAP 5120     // per-bin edge capacity: mean ~4082, +16 sigma
#define TILE_B 4096   // edges per sort tile (16 per thread) — measured optimum

typedef __attribute__((ext_vector_type(8))) short short8v;   // 8 bf16
typedef __attribute__((ext_vector_type(4))) float f32x4v;    // 4 f32 acc

__device__ __forceinline__ unsigned pk_bf16(float a, float b) {  // 2xf32 -> packed bf16 (RNE)
    unsigned ua = __builtin_bit_cast(unsigned, a);
    unsigned ub = __builtin_bit_cast(unsigned, b);
    ua = (ua + 0x7FFFu + ((ua >> 16) & 1u)) >> 16;
    ub = (ub + 0x7FFFu + ((ub >> 16) & 1u)) >> 16;
    return ua | (ub << 16);
}

// ---------------------------------------------------------------------------
// P1 fused: (A) support GEMM via bf16 MFMA 16x16x32 — x staged bf16 in LDS,
//               W fragments loaded per-lane from fp32 global (L2-hot) with
//               in-register bf16 convert; 4 waves x 16 MFMA per 32-row block.
//           (B) tile counting-sort, 4096 edges/tile (measured-optimal).
__global__ __launch_bounds__(256) void p1_kernel(const float* __restrict__ x,
                                                 const float* __restrict__ weight,
                                                 __half* __restrict__ sup,
                                                 const int* __restrict__ eidx,
                                                 int* __restrict__ gcur,
                                                 int* __restrict__ part,
                                                 int n, int e_total, int sblocks) {
    const int t = threadIdx.x;
    __shared__ unsigned short xb[32][72];          // 4.6 KB bf16 x-tile (pad->16B-aligned chunks)
    __shared__ int hist[NBINMAX], lbase[NBINMAX], gbase[NBINMAX];
    __shared__ int wsum[4];

    // ---- phase A ----
    const int rowbase = blockIdx.x * 32;
    if (rowbase < n) {
        {   // stage x tile as bf16
            int nrows = n - rowbase; if (nrows > 32) nrows = 32;
            int nf2 = nrows * 32;                  // float2 count
            const float2* __restrict__ x2 = (const float2*)(x + (size_t)rowbase * 64);
            #pragma unroll
            for (int j = 0; j < 4; ++j) {
                int idx = t + j * 256;
                if (idx < nf2) {
                    float2 v = x2[idx];
                    int r = idx >> 5, c2 = idx & 31;
                    *(unsigned*)&xb[r][c2 * 2] = pk_bf16(v.x, v.y);
                }
            }
        }
        __syncthreads();

        const int lane = t & 63;
        const int w4 = t >> 6;                     // wave id: owns cols [w4*64, w4*64+64)
        const int lm = lane & 15, lg = lane >> 4;

        short8v a[2][2];                           // [mtile][kblock]
        #pragma unroll
        for (int mt = 0; mt < 2; ++mt)
            #pragma unroll
            for (int kb = 0; kb < 2; ++kb)
                a[mt][kb] = *(const short8v*)&xb[mt * 16 + lm][kb * 32 + lg * 8];

        f32x4v acc[2][4];
        #pragma unroll
        for (int mt = 0; mt < 2; ++mt)
            #pragma unroll
            for (int nt = 0; nt < 4; ++nt)
                acc[mt][nt] = (f32x4v){0.f, 0.f, 0.f, 0.f};

        #pragma unroll
        for (int nt = 0; nt < 4; ++nt) {
            const int col = (w4 * 4 + nt) * 16 + lm;
            short8v bfr[2];
            #pragma unroll
            for (int kb = 0; kb < 2; ++kb) {
                short8v bb;
                #pragma unroll
                for (int j = 0; j < 8; ++j) {
                    float wv = weight[(kb * 32 + lg * 8 + j) * 256 + col];
                    unsigned u = __builtin_bit_cast(unsigned, wv);
                    bb[j] = (short)((u + 0x7FFFu + ((u >> 16) & 1u)) >> 16);
                }
                bfr[kb] = bb;
            }
            #pragma unroll
            for (int mt = 0; mt < 2; ++mt) {
                acc[mt][nt] = __builtin_amdgcn_mfma_f32_16x16x32_bf16(a[mt][0], bfr[0], acc[mt][nt], 0, 0, 0);
                acc[mt][nt] = __builtin_amdgcn_mfma_f32_16x16x32_bf16(a[mt][1], bfr[1], acc[mt][nt], 0, 0, 0);
            }
        }

        // epilogue: C layout col=lane&15, row=(lane>>4)*4+reg (m89-verified)
        #pragma unroll
        for (int mt = 0; mt < 2; ++mt) {
            const int row0 = rowbase + mt * 16 + lg * 4;
            #pragma unroll
            for (int reg = 0; reg < 4; ++reg) {
                if (row0 + reg < n) {
                    #pragma unroll
                    for (int nt = 0; nt < 4; ++nt) {
                        int col = (w4 * 4 + nt) * 16 + lm;
                        sup[(size_t)(row0 + reg) * 256 + col] = __float2half(acc[mt][nt][reg]);
                    }
                }
            }
        }
    }

    // ---- phase B: counting-sort a 4096-edge tile (blocks < sblocks) ----
    if (blockIdx.x < sblocks) {
        int nz = 0;
        #pragma unroll
        for (int j = 1; j < 16; j += 2) nz |= eidx[j];   // broadcast scalar loads
        const int is64 = (nz == 0);

        hist[t] = 0;
        __syncthreads();

        const int base = blockIdx.x * TILE_B;
        int nv = e_total - base;
        if (nv > TILE_B) nv = TILE_B;
        if (nv < 0) nv = 0;

        int pay[16], bn[16], lp[16];
        #pragma unroll
        for (int i = 0; i < 8; ++i) {
            const int pl = t + 256 * i;              // local pair id
            const int pg = (base >> 1) + pl;         // global pair id
            int r0 = 0, c0 = 0, r1 = 0, c1 = 0, v0 = 0, v1 = 0;
            if (2 * pl < nv) {
                if (is64) {
                    int4 rr = ((const int4*)eidx)[pg];
                    int4 cc = ((const int4*)(eidx + 2 * (size_t)e_total))[pg];
                    r0 = rr.x; c0 = cc.x; v0 = 1;
                    if (2 * pl + 1 < nv) { r1 = rr.z; c1 = cc.z; v1 = 1; }
                } else {
                    int2 rr = ((const int2*)eidx)[pg];
                    int2 cc = ((const int2*)(eidx + (size_t)e_total))[pg];
                    r0 = rr.x; c0 = cc.x; v0 = 1;
                    if (2 * pl + 1 < nv) { r1 = rr.y; c1 = cc.y; v1 = 1; }
                }
            }
            pay[2 * i]     = (c0 << 8) | (r0 & 255);
            bn[2 * i]      = v0 ? (r0 >> BINSH) : -1;
            pay[2 * i + 1] = (c1 << 8) | (r1 & 255);
            bn[2 * i + 1]  = v1 ? (r1 >> BINSH) : -1;
        }
        #pragma unroll
        for (int i = 0; i < 16; ++i) {
            lp[i] = (bn[i] >= 0) ? atomicAdd(&hist[bn[i]], 1) : 0;
        }
        __syncthreads();

        {   // block exclusive scan over 256 hist entries
            const int lane = t & 63;
            const int w = t >> 6;
            int h = hist[t];
            int s = h;
            #pragma unroll
            for (int off = 1; off < 64; off <<= 1) {
                int u = __shfl_up(s, off, 64);
                if (lane >= off) s += u;
            }
            if (lane == 63) wsum[w] = s;
            __syncthreads();
            if (t == 0) {
                int a0 = 0;
                #pragma unroll
                for (int q = 0; q < 4; ++q) { int u = wsum[q]; wsum[q] = a0; a0 += u; }
            }
            __syncthreads();
            lbase[t] = s - h + wsum[w];
            gbase[t] = (h > 0) ? atomicAdd(&gcur[t], h) : 0;
        }
        __syncthreads();

        #pragma unroll
        for (int i = 0; i < 16; ++i) {
            if (bn[i] >= 0) {
                int dst = gbase[bn[i]] + lp[i];
                if (dst < PCAP) part[bn[i] * PCAP + dst] = pay[i];
            }
        }
    }
}

// ---------------------------------------------------------------------------
// P2: one block per 256-row bin; re-bucket into row-CSR AND precompute the
// Gaussian values. Stores col (4B) + packed 4xfp16 values (8B) per edge.
__global__ __launch_bounds__(1024) void p2_kernel(const int* __restrict__ gcur,
                                                  const int* __restrict__ part,
                                                  const float* __restrict__ spec,
                                                  const float* __restrict__ mu,   // [3][4]
                                                  const float* __restrict__ sig,  // [4]
                                                  int* __restrict__ cnt,
                                                  int* __restrict__ scol,
                                                  uint2* __restrict__ sval, int n) {
    __shared__ int cl[256];
    const int t = threadIdx.x;
    const int b = blockIdx.x;
    const int row0 = b << BINSH;
    if (t < 256) cl[t] = 0;
    __syncthreads();

    float m0[4], m1[4], m2[4], sg[4];
    #pragma unroll
    for (int k = 0; k < 4; ++k) {
        m0[k] = mu[k]; m1[k] = mu[4 + k]; m2[k] = mu[8 + k]; sg[k] = sig[k];
    }

    int nloc = gcur[b];
    if (nloc > PCAP) nloc = PCAP;
    const int* __restrict__ mypart = part + b * PCAP;

    for (int i = t; i < nloc; i += 1024) {
        int e = mypart[i];
        int rl = e & 255;
        int col = ((unsigned)e) >> 8;
        int row = row0 + rl;

        float d0 = spec[row * 3 + 0] - spec[col * 3 + 0];
        float d1 = spec[row * 3 + 1] - spec[col * 3 + 1];
        float d2 = spec[row * 3 + 2] - spec[col * 3 + 2];
        float v[4];
        #pragma unroll
        for (int k = 0; k < 4; ++k) {
            float a = d0 - m0[k], bb = d1 - m1[k], c = d2 - m2[k];
            v[k] = __expf(sg[k] * (-0.5f * (a * a + bb * bb + c * c)));
        }
        union { __half2 h; unsigned u; } p01, p23;
        p01.h = __floats2half2_rn(v[0], v[1]);
        p23.h = __floats2half2_rn(v[2], v[3]);

        int pos = atomicAdd(&cl[rl], 1);
        if (pos < CAP) {
            scol[(size_t)row * CAP + pos] = col;
            sval[(size_t)row * CAP + pos] = make_uint2(p01.u, p23.u);
        }
    }
    __syncthreads();

    int row = row0 + t;
    if (t < 256 && row < n) cnt[row] = (cl[t] > CAP) ? CAP : cl[t];
}

// ---------------------------------------------------------------------------
__device__ __forceinline__ float dot_supv(uint2 p, uint2 pv) {
    float2 f0 = __half22float2(__builtin_bit_cast(__half2, p.x));
    float2 f1 = __half22float2(__builtin_bit_cast(__half2, p.y));
    float2 a0 = __half22float2(__builtin_bit_cast(__half2, pv.x));
    float2 a1 = __half22float2(__builtin_bit_cast(__half2, pv.y));
    return f0.x * a0.x + f0.y * a0.y + f1.x * a1.x + f1.y * a1.y;
}

// One wave per row (grid-stride). 16-deep gather chunks; pad slots masked.
__global__ __launch_bounds__(256, 6) void row_kernel(const int* __restrict__ cnt,
                                                     const int* __restrict__ scol,
                                                     const uint2* __restrict__ sval,
                                                     const __half* __restrict__ sup,
                                                     const float* __restrict__ bias,
                                                     float* __restrict__ out, int n) {
    const int lane = threadIdx.x & 63;
    const int wl = threadIdx.x >> 6;
    const int wv = __builtin_amdgcn_readfirstlane(blockIdx.x * 4 + wl);
    const int NW = gridDim.x * 4;
    const float bias_l = bias[lane];
    const unsigned un = (unsigned)n;

    for (int r = wv; r < n; r += NW) {
        int ec = cnt[r];                          // uniform -> s_load
        if (ec > CAP) ec = CAP;
        const size_t base = (size_t)r * CAP;
        float acc = bias_l;

        for (int j = 0; j < ec; j += 16) {
            int c[16]; uint2 w[16];
            #pragma unroll
            for (int i = 0; i < 16; ++i) {
                int idx = j + i;                  // idx <= 47 < CAP always
                int cc = scol[base + idx];        // uniform -> s_load
                uint2 ww = sval[base + idx];
                bool valid = idx < ec;
                c[i] = ((unsigned)cc < un) ? cc : 0;
                w[i] = valid ? ww : make_uint2(0u, 0u);
            }
            uint2 p[16];
            #pragma unroll
            for (int i = 0; i < 16; ++i)
                p[i] = *(const uint2*)(sup + ((size_t)c[i] * 256 + lane * 4));
            #pragma unroll
            for (int i = 0; i < 16; ++i)
                acc += dot_supv(p[i], w[i]);
        }
        out[(size_t)r * 64 + lane] = acc;
    }
}

// ---------------------------------------------------------------------------
extern "C" void kernel_launch(void* const* d_in, const int* in_sizes, int n_in,
                              void* d_out, int out_size, void* d_ws, size_t ws_size,
                              hipStream_t stream) {
    const float* x      = (const float*)d_in[0];
    const int*   eidx   = (const int*)d_in[1];
    const float* spec   = (const float*)d_in[2];
    const float* weight = (const float*)d_in[3];
    const float* bias   = (const float*)d_in[4];
    const float* mu     = (const float*)d_in[5];
    const float* sig    = (const float*)d_in[6];
    float* out = (float*)d_out;

    const int N = in_sizes[0] / FIN;               // 50000
    const int E = in_sizes[1] / 2;                 // 800000
    const int NB32 = (N + 31) / 32;                // 1563 (covers 196 sort tiles)
    const int SBLK = (E + TILE_B - 1) / TILE_B;    // 196 sort tiles
    const int NBIN = (N + (1 << BINSH) - 1) >> BINSH;  // 196 bins

    char* w = (char*)d_ws;
    size_t off = 0;
    int* gcur = (int*)(w + off);            off += NBINMAX * 4;
    __half* sup = (__half*)(w + off);       off += (size_t)N * 256 * sizeof(__half);  // 25.6 MB
    off = (off + 255) & ~(size_t)255;
    int* cnt = (int*)(w + off);             off += (size_t)N * 4;
    off = (off + 255) & ~(size_t)255;
    int* scol = (int*)(w + off);            off += (size_t)N * CAP * 4;       // 9.6 MB
    off = (off + 255) & ~(size_t)255;
    uint2* sval = (uint2*)(w + off);        off += (size_t)N * CAP * 8;       // 19.2 MB
    off = (off + 255) & ~(size_t)255;
    int* part = (int*)(w + off);            off += (size_t)NBIN * PCAP * 4;   // 4 MB

    hipMemsetAsync(gcur, 0, NBINMAX * 4, stream);
    p1_kernel<<<NB32, 256, 0, stream>>>(x, weight, sup, eidx, gcur, part, N, E, SBLK);
    p2_kernel<<<NBIN, 1024, 0, stream>>>(gcur, part, spec, mu, sig, cnt, scol, sval, N);
    row_kernel<<<1536, 256, 0, stream>>>(cnt, scol, sval, sup, bias, out, N);
}